// Round 6
// baseline (3106.301 us; speedup 1.0000x reference)
//
#include <hip/hip_runtime.h>
#include <hip/hip_bf16.h>

// Problem constants
#define DD 2048
#define TT 512
#define NBLK 64           // recurrence workgroups (plus NBLK y-consumer workgroups)
#define HF_SLOT 32768     // elements per h fragment slot (16 x 2048)
#define KT 64             // K tiles of 32 (DD/32)

typedef __attribute__((ext_vector_type(4))) float  f32x4;
typedef __attribute__((ext_vector_type(8))) short  bf16x8;
typedef __attribute__((ext_vector_type(8))) unsigned short u16x8;
typedef unsigned short ushort_t;
typedef unsigned long long u64_t;

__device__ __forceinline__ void gld_lds16(const void* g, void* l) {
    __builtin_amdgcn_global_load_lds(
        (const __attribute__((address_space(1))) unsigned int*)g,
        (__attribute__((address_space(3))) unsigned int*)l, 16, 0, 0);
}

__device__ __forceinline__ ushort_t f2bf(float v) {
    __hip_bfloat16 h = __float2bfloat16(v);
    return *(ushort_t*)&h;
}

// LLC-coherent (agent-scope, relaxed) accessors — no wbl2/inv emitted.
__device__ __forceinline__ u64_t llc_load64(const u64_t* p) {
    return __hip_atomic_load(p, __ATOMIC_RELAXED, __HIP_MEMORY_SCOPE_AGENT);
}
__device__ __forceinline__ void llc_store64(u64_t* p, u64_t v) {
    __hip_atomic_store(p, v, __ATOMIC_RELAXED, __HIP_MEMORY_SCOPE_AGENT);
}
__device__ __forceinline__ unsigned llc_load32(const unsigned* p) {
    return __hip_atomic_load(p, __ATOMIC_RELAXED, __HIP_MEMORY_SCOPE_AGENT);
}
__device__ __forceinline__ float llc_loadf(const float* p) {
    return __hip_atomic_load(p, __ATOMIC_RELAXED, __HIP_MEMORY_SCOPE_AGENT);
}

// 16 B LLC-bypass load/store (same L1+L2 bypass as agent-scope atomics,
// half the request count of 2x llc_load64). Manual vmcnt discipline!
#define LLC_LOAD16(dst, ptr) \
    asm volatile("global_load_dwordx4 %0, %1, off sc0 sc1" : "=v"(dst) : "v"(ptr) : "memory")
#define LLC_STORE16(ptr, val) \
    asm volatile("global_store_dwordx4 %0, %1, off sc0 sc1" :: "v"(ptr), "v"(val) : "memory")

// ---------------------------------------------------------------------------
// Convert fp32 row-major [mtiles*16][2048] -> bf16 A-fragment layout
// ---------------------------------------------------------------------------
__global__ void conv_frag(const float* __restrict__ src, ushort_t* __restrict__ dst) {
    int id = blockIdx.x * 256 + threadIdx.x;     // one thread per 8 elements
    int l  = id & 63;
    int sk = (id >> 6) & 63;
    int mt = id >> 12;
    const float* s = src + (size_t)(mt * 16 + (l & 15)) * DD + sk * 32 + ((l >> 4) * 8);
    float4 a = *(const float4*)s;
    float4 b = *(const float4*)(s + 4);
    u16x8 r;
    r[0] = f2bf(a.x); r[1] = f2bf(a.y); r[2] = f2bf(a.z); r[3] = f2bf(a.w);
    r[4] = f2bf(b.x); r[5] = f2bf(b.y); r[6] = f2bf(b.z); r[7] = f2bf(b.w);
    *(u16x8*)(dst + (size_t)id * 8) = r;
}

// ---------------------------------------------------------------------------
// Transpose fp32 W[k][n] -> bf16 Wt[n][k]
// ---------------------------------------------------------------------------
__global__ void conv_wt(const float* __restrict__ W, ushort_t* __restrict__ Wt) {
    int id = blockIdx.x * 256 + threadIdx.x;
    int n  = id & (DD - 1);
    int k8 = id >> 11;
    u16x8 r;
#pragma unroll
    for (int j = 0; j < 8; ++j)
        r[j] = f2bf(W[(size_t)(k8 * 8 + j) * DD + n]);
    *(u16x8*)(Wt + (size_t)n * DD + k8 * 8) = r;
}

// ---------------------------------------------------------------------------
// m97-style GEMM: C[M x 2048] = Af @ Bt^T  (phase 1 only)
// ---------------------------------------------------------------------------
__global__ __launch_bounds__(256) void gemm_frag(
    const ushort_t* __restrict__ Af, const ushort_t* __restrict__ Bt,
    float* __restrict__ C) {
    __shared__ ushort_t lA[8 * 64 * 8];
    __shared__ ushort_t lB[8 * 64 * 8];
    int tid = threadIdx.x;
    int w = tid >> 6, l = tid & 63;
    int wm = w >> 1, wn = w & 1;
    int quad = l >> 4, col = l & 15;
    int mt0 = blockIdx.x * 8;
    int n0  = blockIdx.y * 128;

    f32x4 acc[4][4] = {};

    for (int sk = 0; sk < KT; ++sk) {
        __syncthreads();
#pragma unroll
        for (int q = 0; q < 2; ++q) {
            int i = w * 2 + q;
            const ushort_t* ga = Af + ((size_t)((mt0 + i) * 64 + sk) * 64 + l) * 8;
            gld_lds16(ga, &lA[i * 512]);
            int jt = i;
            const ushort_t* gb = Bt + (size_t)(n0 + jt * 16 + col) * DD + sk * 32 + quad * 8;
            gld_lds16(gb, &lB[jt * 512]);
        }
        __syncthreads();
        bf16x8 af[4], bf[4];
#pragma unroll
        for (int i = 0; i < 4; ++i) af[i] = *(const bf16x8*)&lA[((wm * 4 + i) * 64 + l) * 8];
#pragma unroll
        for (int j = 0; j < 4; ++j) bf[j] = *(const bf16x8*)&lB[((wn * 4 + j) * 64 + l) * 8];
#pragma unroll
        for (int i = 0; i < 4; ++i)
#pragma unroll
            for (int j = 0; j < 4; ++j)
                acc[i][j] = __builtin_amdgcn_mfma_f32_16x16x32_bf16(af[i], bf[j], acc[i][j], 0, 0, 0);
    }

#pragma unroll
    for (int i = 0; i < 4; ++i)
#pragma unroll
        for (int j = 0; j < 4; ++j) {
            int rg0 = (mt0 + wm * 4 + i) * 16 + quad * 4;
            int cg  = n0 + (wn * 4 + j) * 16 + col;
#pragma unroll
            for (int r = 0; r < 4; ++r)
                C[(size_t)(rg0 + r) * DD + cg] = acc[i][j][r];
        }
}

// ---------------------------------------------------------------------------
// Fused recurrence + y-GEMM consumers. 128 blocks x 256 threads.
//   blocks 0..63   : recurrence, column slice 32*b, publish h_t + flag
//   blocks 64..127 : y = h_t @ Wo slice, consume flags, write ys fp32
// Round-0 sync protocol verbatim (single-wave poll + barrier broadcast,
// ack-then-flag publish). Latency micro-cuts only:
//   - flags PACKED into one 256 B span (u32 per producer): poll = one
//     coalesced 4-line read instead of max-of-64 padded lines (MALL has no
//     line-ownership migration, so false-sharing padding buys nothing)
//   - h loads as 16 x dwordx4 sc0 sc1 (vs 32 x 8 B atomics), one manual
//     vmcnt(0) drain + sched_barrier (rule 18)
//   - publish as one dwordx4 store per lane (ack drains 1 store, not 2)
//   - 4 independent 8-deep MFMA chains (vs 2 x 16-deep)
// ---------------------------------------------------------------------------
__global__ __launch_bounds__(256, 1) void rnn_fused(
    const ushort_t* __restrict__ Wht,   // bf16 [n][k]
    const ushort_t* __restrict__ Wot,   // bf16 [n][k]
    ushort_t* __restrict__ Hf,          // (TT+1) slots of A-fragment h
    const float* __restrict__ A32,      // fp32 [TT*16][2048] = x@Wx (aliases ys!)
    float* __restrict__ out,            // [0:HF_SLOT) h_final, then ys
    unsigned* __restrict__ flags) {     // NBLK packed u32 flags, zeroed
    __shared__ ushort_t lW[4 * 16 * 2 * 512];   // 128 KB (Wh or Wo slice)
    __shared__ float scr[2048];                 // 8 KB reduction scratch
    __shared__ ushort_t hstage[512];            // 1 KB h-output staging (rnn only)
    int tid = threadIdx.x;
    int w = tid >> 6, l = tid & 63;
    int quad = l >> 4, col = l & 15;
    bool is_rnn = blockIdx.x < NBLK;
    int b = is_rnn ? blockIdx.x : blockIdx.x - NBLK;
    int c0 = b * 32;
    float* ys = out + HF_SLOT;

    // Stage this block's weight slice (2048 K x 32 N) into LDS.
    const ushort_t* Wsrc = is_rnn ? Wht : Wot;
#pragma unroll
    for (int s = 0; s < 16; ++s) {
        int sk = w * 16 + s;
#pragma unroll
        for (int jt = 0; jt < 2; ++jt) {
            const ushort_t* gb = Wsrc + (size_t)(c0 + jt * 16 + col) * DD + sk * 32 + quad * 8;
            gld_lds16(gb, &lW[((w * 16 + s) * 2 + jt) << 9]);
        }
    }
    __syncthreads();

    for (int t = 1; t <= TT; ++t) {
        // rnn: prefetch A32 addend before the poll (latency hidden by wait).
        float av[4];
        if (is_rnn && w < 2) {
#pragma unroll
            for (int r = 0; r < 4; ++r)
                av[r] = llc_loadf(&A32[(size_t)((t - 1) * 16 + quad * 4 + r) * DD + c0 + w * 16 + col]);
        }

        // Single-wave poll of the PACKED flag array (one coalesced 256 B
        // read across 4 MALL lines), broadcast via barrier.
        // rnn waits for h_{t-1} (flags >= t-1); y waits for h_t (flags >= t).
        unsigned tgt = is_rnn ? (unsigned)(t - 1) : (unsigned)t;
        if (w == 3) {
            unsigned f;
            do {
                f = llc_load32(&flags[l]);
            } while (!__all((int)(f >= tgt)));
        }
        __syncthreads();

        // Load h fragments from LLC: 16 x dwordx4 (sc0 sc1 = L1+L2 bypass),
        // one drain, sched fence so MFMAs can't hoist above the waitcnt.
        const ushort_t* hsrc = Hf + (size_t)(is_rnn ? t - 1 : t) * HF_SLOT;
        bf16x8 hv[16];
#pragma unroll
        for (int s = 0; s < 16; ++s) {
            int sk = w * 16 + s;
            const char* p = (const char*)hsrc + (size_t)(sk * 64 + l) * 16;
            LLC_LOAD16(hv[s], p);
        }
        asm volatile("s_waitcnt vmcnt(0)" ::: "memory");
        __builtin_amdgcn_sched_barrier(0);

        f32x4 a0e = {0.f, 0.f, 0.f, 0.f}, a0o = {0.f, 0.f, 0.f, 0.f};
        f32x4 a1e = {0.f, 0.f, 0.f, 0.f}, a1o = {0.f, 0.f, 0.f, 0.f};
#pragma unroll
        for (int s = 0; s < 16; ++s) {
            bf16x8 w0 = *(const bf16x8*)&lW[(((w * 16 + s) * 2 + 0) << 9) + l * 8];
            bf16x8 w1 = *(const bf16x8*)&lW[(((w * 16 + s) * 2 + 1) << 9) + l * 8];
            if (s & 1) {
                a0o = __builtin_amdgcn_mfma_f32_16x16x32_bf16(hv[s], w0, a0o, 0, 0, 0);
                a1o = __builtin_amdgcn_mfma_f32_16x16x32_bf16(hv[s], w1, a1o, 0, 0, 0);
            } else {
                a0e = __builtin_amdgcn_mfma_f32_16x16x32_bf16(hv[s], w0, a0e, 0, 0, 0);
                a1e = __builtin_amdgcn_mfma_f32_16x16x32_bf16(hv[s], w1, a1e, 0, 0, 0);
            }
        }
        f32x4 acc0 = a0e + a0o;
        f32x4 acc1 = a1e + a1o;

        *(f32x4*)&scr[((w * 2 + 0) * 64 + l) * 4] = acc0;
        *(f32x4*)&scr[((w * 2 + 1) * 64 + l) * 4] = acc1;
        __syncthreads();   // scr ready

        if (w < 2) {   // waves 0,1 finish the 2 column tiles
            int jt = w;
            f32x4 p0 = *(f32x4*)&scr[((0 * 2 + jt) * 64 + l) * 4];
            f32x4 p1 = *(f32x4*)&scr[((1 * 2 + jt) * 64 + l) * 4];
            f32x4 p2 = *(f32x4*)&scr[((2 * 2 + jt) * 64 + l) * 4];
            f32x4 p3 = *(f32x4*)&scr[((3 * 2 + jt) * 64 + l) * 4];
            int lc = jt * 16 + col;          // 0..31 within block's column slice
            if (is_rnn) {
                int q2 = lc >> 3, jj = lc & 7;
#pragma unroll
                for (int r = 0; r < 4; ++r) {
                    int m = quad * 4 + r;    // C/D layout: row=(l>>4)*4+r
                    float x = p0[r] + p1[r] + p2[r] + p3[r] + av[r];
                    float e2 = __expf(-2.f * fabsf(x));
                    float th = copysignf((1.f - e2) / (1.f + e2), x);
                    hstage[(q2 * 16 + m) * 8 + jj] = f2bf(th);
                    if (t == TT) out[(size_t)m * DD + c0 + lc] = th;
                }
            } else {
#pragma unroll
                for (int r = 0; r < 4; ++r) {
                    int m = quad * 4 + r;
                    float y = p0[r] + p1[r] + p2[r] + p3[r];
                    ys[(size_t)((t - 1) * 16 + m) * DD + c0 + lc] = y;
                }
            }
        }

        if (is_rnn) {
            __syncthreads();   // hstage complete
            // Wave 0 publishes the block's 1 KB h slice (one 16 B store per
            // lane), acks, then stores its packed flag.
            if (w == 0) {
                char* dst = (char*)(Hf + (size_t)t * HF_SLOT + (size_t)b * 512) + l * 16;
                f32x4 v = *(const f32x4*)((const char*)hstage + l * 16);
                LLC_STORE16(dst, v);
                asm volatile("s_waitcnt vmcnt(0)" ::: "memory");   // store acked at LLC
                if (l == 0)
                    __hip_atomic_store(&flags[b], (unsigned)t,
                                       __ATOMIC_RELAXED, __HIP_MEMORY_SCOPE_AGENT);
            }
        }
        // y blocks: scr reuse at t+1 protected by the next poll barrier.
    }
}

// ---------------------------------------------------------------------------
extern "C" void kernel_launch(void* const* d_in, const int* in_sizes, int n_in,
                              void* d_out, int out_size, void* d_ws, size_t ws_size,
                              hipStream_t stream) {
    const float* h0 = (const float*)d_in[0];
    const float* x  = (const float*)d_in[1];
    const float* Wx = (const float*)d_in[2];
    const float* Wh = (const float*)d_in[3];
    const float* Wo = (const float*)d_in[4];
    float* out = (float*)d_out;

    char* ws = (char*)d_ws;
    unsigned* flags = (unsigned*)ws;                             // 256 B packed (64 u32)
    ushort_t* Hf  = (ushort_t*)(ws + 4096);                      // 513 slots * 64KB
    ushort_t* Xf  = Hf + HF_SLOT;                                // alias slots 1..512 (dead after phase 1)
    size_t hf_bytes = (size_t)(TT + 1) * HF_SLOT * 2;
    ushort_t* Wxt = (ushort_t*)(ws + 4096 + hf_bytes);
    ushort_t* Wht = Wxt + (size_t)DD * DD;
    ushort_t* Wot = Wht + (size_t)DD * DD;
    float* A32 = out + HF_SLOT;                                  // ys region; y writes trail A32 reads

    hipMemsetAsync(d_ws, 0, 4096, stream);

    // fp32 -> bf16 layout conversions
    conv_frag<<<8192, 256, 0, stream>>>(x, Xf);                  // X fragments
    conv_frag<<<16, 256, 0, stream>>>(h0, Hf);                   // h0 -> slot 0
    conv_wt<<<2048, 256, 0, stream>>>(Wx, Wxt);
    conv_wt<<<2048, 256, 0, stream>>>(Wh, Wht);
    conv_wt<<<2048, 256, 0, stream>>>(Wo, Wot);

    // Phase 1: A32 = X @ Wx   (fp32, lives in d_out's ys region)
    gemm_frag<<<dim3(64, 16), 256, 0, stream>>>(Xf, Wxt, A32);

    // Phase 2+3 fused: recurrence + streaming y = h @ Wo
    rnn_fused<<<2 * NBLK, 256, 0, stream>>>(Wht, Wot, Hf, A32, out, flags);
}

// Round 7
// 2000.152 us; speedup vs baseline: 1.5530x; 1.5530x over previous
//
#include <hip/hip_runtime.h>
#include <hip/hip_bf16.h>

// Problem constants
#define DD 2048
#define TT 512
#define NBLK 64           // recurrence workgroups (plus NBLK y-consumer workgroups)
#define HF_SLOT 32768     // elements per h fragment slot (16 x 2048)
#define KT 64             // K tiles of 32 (DD/32)
#define FSTRIDE 16        // dwords between flags (64 B -> one LLC line each; 1 writer per line)

typedef __attribute__((ext_vector_type(4))) float  f32x4;
typedef __attribute__((ext_vector_type(8))) short  bf16x8;
typedef __attribute__((ext_vector_type(8))) unsigned short u16x8;
typedef unsigned short ushort_t;
typedef unsigned long long u64_t;

__device__ __forceinline__ void gld_lds16(const void* g, void* l) {
    __builtin_amdgcn_global_load_lds(
        (const __attribute__((address_space(1))) unsigned int*)g,
        (__attribute__((address_space(3))) unsigned int*)l, 16, 0, 0);
}

__device__ __forceinline__ ushort_t f2bf(float v) {
    __hip_bfloat16 h = __float2bfloat16(v);
    return *(ushort_t*)&h;
}

// LLC-coherent (agent-scope, relaxed) accessors — no wbl2/inv emitted.
__device__ __forceinline__ float llc_loadf(const float* p) {
    return __hip_atomic_load(p, __ATOMIC_RELAXED, __HIP_MEMORY_SCOPE_AGENT);
}

// 16 B LLC-bypass load/store (same L1+L2 bypass as agent-scope atomics,
// half the request count of 2x 8 B atomics). Manual vmcnt discipline.
#define LLC_LOAD16(dst, ptr) \
    asm volatile("global_load_dwordx4 %0, %1, off sc0 sc1" : "=v"(dst) : "v"(ptr) : "memory")
#define LLC_STORE16(ptr, val) \
    asm volatile("global_store_dwordx4 %0, %1, off sc0 sc1" :: "v"(ptr), "v"(val) : "memory")
#define POLL_LOAD(r, p) \
    asm volatile("global_load_dword %0, %1, off sc0 sc1" : "=v"(r) : "v"(p) : "memory")

// ---------------------------------------------------------------------------
// Convert fp32 row-major [mtiles*16][2048] -> bf16 A-fragment layout
// ---------------------------------------------------------------------------
__global__ void conv_frag(const float* __restrict__ src, ushort_t* __restrict__ dst) {
    int id = blockIdx.x * 256 + threadIdx.x;     // one thread per 8 elements
    int l  = id & 63;
    int sk = (id >> 6) & 63;
    int mt = id >> 12;
    const float* s = src + (size_t)(mt * 16 + (l & 15)) * DD + sk * 32 + ((l >> 4) * 8);
    float4 a = *(const float4*)s;
    float4 b = *(const float4*)(s + 4);
    u16x8 r;
    r[0] = f2bf(a.x); r[1] = f2bf(a.y); r[2] = f2bf(a.z); r[3] = f2bf(a.w);
    r[4] = f2bf(b.x); r[5] = f2bf(b.y); r[6] = f2bf(b.z); r[7] = f2bf(b.w);
    *(u16x8*)(dst + (size_t)id * 8) = r;
}

// ---------------------------------------------------------------------------
// Transpose fp32 W[k][n] -> bf16 Wt[n][k]
// ---------------------------------------------------------------------------
__global__ void conv_wt(const float* __restrict__ W, ushort_t* __restrict__ Wt) {
    int id = blockIdx.x * 256 + threadIdx.x;
    int n  = id & (DD - 1);
    int k8 = id >> 11;
    u16x8 r;
#pragma unroll
    for (int j = 0; j < 8; ++j)
        r[j] = f2bf(W[(size_t)(k8 * 8 + j) * DD + n]);
    *(u16x8*)(Wt + (size_t)n * DD + k8 * 8) = r;
}

// ---------------------------------------------------------------------------
// m97-style GEMM: C[M x 2048] = Af @ Bt^T  (phase 1 only)
// ---------------------------------------------------------------------------
__global__ __launch_bounds__(256) void gemm_frag(
    const ushort_t* __restrict__ Af, const ushort_t* __restrict__ Bt,
    float* __restrict__ C) {
    __shared__ ushort_t lA[8 * 64 * 8];
    __shared__ ushort_t lB[8 * 64 * 8];
    int tid = threadIdx.x;
    int w = tid >> 6, l = tid & 63;
    int wm = w >> 1, wn = w & 1;
    int quad = l >> 4, col = l & 15;
    int mt0 = blockIdx.x * 8;
    int n0  = blockIdx.y * 128;

    f32x4 acc[4][4] = {};

    for (int sk = 0; sk < KT; ++sk) {
        __syncthreads();
#pragma unroll
        for (int q = 0; q < 2; ++q) {
            int i = w * 2 + q;
            const ushort_t* ga = Af + ((size_t)((mt0 + i) * 64 + sk) * 64 + l) * 8;
            gld_lds16(ga, &lA[i * 512]);
            int jt = i;
            const ushort_t* gb = Bt + (size_t)(n0 + jt * 16 + col) * DD + sk * 32 + quad * 8;
            gld_lds16(gb, &lB[jt * 512]);
        }
        __syncthreads();
        bf16x8 af[4], bf[4];
#pragma unroll
        for (int i = 0; i < 4; ++i) af[i] = *(const bf16x8*)&lA[((wm * 4 + i) * 64 + l) * 8];
#pragma unroll
        for (int j = 0; j < 4; ++j) bf[j] = *(const bf16x8*)&lB[((wn * 4 + j) * 64 + l) * 8];
#pragma unroll
        for (int i = 0; i < 4; ++i)
#pragma unroll
            for (int j = 0; j < 4; ++j)
                acc[i][j] = __builtin_amdgcn_mfma_f32_16x16x32_bf16(af[i], bf[j], acc[i][j], 0, 0, 0);
    }

#pragma unroll
    for (int i = 0; i < 4; ++i)
#pragma unroll
        for (int j = 0; j < 4; ++j) {
            int rg0 = (mt0 + wm * 4 + i) * 16 + quad * 4;
            int cg  = n0 + (wn * 4 + j) * 16 + col;
#pragma unroll
            for (int r = 0; r < 4; ++r)
                C[(size_t)(rg0 + r) * DD + cg] = acc[i][j][r];
        }
}

// ---------------------------------------------------------------------------
// Fused recurrence + y-GEMM consumers. 128 blocks x 256 threads.
//   blocks 0..63   : recurrence, column slice 32*b, publish h_t + flag
//   blocks 64..127 : y = h_t @ Wo slice, consume flags, write ys fp32
// Round-0 protocol verbatim: padded per-producer flag lines (1 writer/line),
// single-wave (w==3) poll + barrier broadcast, ack-then-flag publish.
// Latency-only deltas vs round 0:
//   - software-pipelined poll: 2 flag loads in flight, alternating; halves
//     detect quantization from ~RT to ~RT/2
//   - h loads as 16 x dwordx4 sc0 sc1 + single vmcnt(0) drain
//   - publish as 1 x 16 B store per lane (ack drains 1 store)
//   - even/odd MFMA accumulator split (ILP)
// ---------------------------------------------------------------------------
__global__ __launch_bounds__(256, 1) void rnn_fused(
    const ushort_t* __restrict__ Wht,   // bf16 [n][k]
    const ushort_t* __restrict__ Wot,   // bf16 [n][k]
    ushort_t* __restrict__ Hf,          // (TT+1) slots of A-fragment h
    const float* __restrict__ A32,      // fp32 [TT*16][2048] = x@Wx (aliases ys!)
    float* __restrict__ out,            // [0:HF_SLOT) h_final, then ys
    unsigned* __restrict__ flags) {     // NBLK flags, 64B stride, zeroed
    __shared__ ushort_t lW[4 * 16 * 2 * 512];   // 128 KB (Wh or Wo slice)
    __shared__ float scr[2048];                 // 8 KB reduction scratch
    __shared__ ushort_t hstage[512];            // 1 KB h-output staging (rnn only)
    int tid = threadIdx.x;
    int w = tid >> 6, l = tid & 63;
    int quad = l >> 4, col = l & 15;
    bool is_rnn = blockIdx.x < NBLK;
    int b = is_rnn ? blockIdx.x : blockIdx.x - NBLK;
    int c0 = b * 32;
    float* ys = out + HF_SLOT;

    // Stage this block's weight slice (2048 K x 32 N) into LDS.
    const ushort_t* Wsrc = is_rnn ? Wht : Wot;
#pragma unroll
    for (int s = 0; s < 16; ++s) {
        int sk = w * 16 + s;
#pragma unroll
        for (int jt = 0; jt < 2; ++jt) {
            const ushort_t* gb = Wsrc + (size_t)(c0 + jt * 16 + col) * DD + sk * 32 + quad * 8;
            gld_lds16(gb, &lW[((w * 16 + s) * 2 + jt) << 9]);
        }
    }
    __syncthreads();

    const unsigned* fp = &flags[l * FSTRIDE];   // poll address (w==3 wave uses it)

    for (int t = 1; t <= TT; ++t) {
        // rnn: prefetch A32 addend before the poll (latency hidden by wait).
        float av[4];
        if (is_rnn && w < 2) {
#pragma unroll
            for (int r = 0; r < 4; ++r)
                av[r] = llc_loadf(&A32[(size_t)((t - 1) * 16 + quad * 4 + r) * DD + c0 + w * 16 + col]);
        }

        // Single-wave pipelined poll (2 in flight), broadcast via barrier.
        // rnn waits for h_{t-1} (flags >= t-1); y waits for h_t (flags >= t).
        unsigned tgt = is_rnn ? (unsigned)(t - 1) : (unsigned)t;
        if (w == 3) {
            unsigned f0, f1;
            POLL_LOAD(f0, fp);
            POLL_LOAD(f1, fp);
            while (true) {
                asm volatile("s_waitcnt vmcnt(1)" ::: "memory");   // f0 ready
                __builtin_amdgcn_sched_barrier(0);
                if (__all((int)(f0 >= tgt))) break;
                POLL_LOAD(f0, fp);                                 // in flight: f1, f0'
                asm volatile("s_waitcnt vmcnt(1)" ::: "memory");   // f1 ready
                __builtin_amdgcn_sched_barrier(0);
                if (__all((int)(f1 >= tgt))) break;
                POLL_LOAD(f1, fp);                                 // in flight: f0', f1'
            }
            asm volatile("s_waitcnt vmcnt(0)" ::: "memory");       // drain stale poll
            __builtin_amdgcn_sched_barrier(0);
        }
        __syncthreads();

        // Load h fragments from LLC: 16 x dwordx4 (sc0 sc1), one drain,
        // sched fence so MFMAs can't hoist above the waitcnt (rule 18).
        const ushort_t* hsrc = Hf + (size_t)(is_rnn ? t - 1 : t) * HF_SLOT;
        bf16x8 hv[16];
#pragma unroll
        for (int s = 0; s < 16; ++s) {
            int sk = w * 16 + s;
            const char* p = (const char*)hsrc + (size_t)(sk * 64 + l) * 16;
            LLC_LOAD16(hv[s], p);
        }
        asm volatile("s_waitcnt vmcnt(0)" ::: "memory");
        __builtin_amdgcn_sched_barrier(0);

        f32x4 a0e = {0.f, 0.f, 0.f, 0.f}, a0o = {0.f, 0.f, 0.f, 0.f};
        f32x4 a1e = {0.f, 0.f, 0.f, 0.f}, a1o = {0.f, 0.f, 0.f, 0.f};
#pragma unroll
        for (int s = 0; s < 16; ++s) {
            bf16x8 w0 = *(const bf16x8*)&lW[(((w * 16 + s) * 2 + 0) << 9) + l * 8];
            bf16x8 w1 = *(const bf16x8*)&lW[(((w * 16 + s) * 2 + 1) << 9) + l * 8];
            if (s & 1) {
                a0o = __builtin_amdgcn_mfma_f32_16x16x32_bf16(hv[s], w0, a0o, 0, 0, 0);
                a1o = __builtin_amdgcn_mfma_f32_16x16x32_bf16(hv[s], w1, a1o, 0, 0, 0);
            } else {
                a0e = __builtin_amdgcn_mfma_f32_16x16x32_bf16(hv[s], w0, a0e, 0, 0, 0);
                a1e = __builtin_amdgcn_mfma_f32_16x16x32_bf16(hv[s], w1, a1e, 0, 0, 0);
            }
        }
        f32x4 acc0 = a0e + a0o;
        f32x4 acc1 = a1e + a1o;

        *(f32x4*)&scr[((w * 2 + 0) * 64 + l) * 4] = acc0;
        *(f32x4*)&scr[((w * 2 + 1) * 64 + l) * 4] = acc1;
        __syncthreads();   // scr ready

        if (w < 2) {   // waves 0,1 finish the 2 column tiles
            int jt = w;
            f32x4 p0 = *(f32x4*)&scr[((0 * 2 + jt) * 64 + l) * 4];
            f32x4 p1 = *(f32x4*)&scr[((1 * 2 + jt) * 64 + l) * 4];
            f32x4 p2 = *(f32x4*)&scr[((2 * 2 + jt) * 64 + l) * 4];
            f32x4 p3 = *(f32x4*)&scr[((3 * 2 + jt) * 64 + l) * 4];
            int lc = jt * 16 + col;          // 0..31 within block's column slice
            if (is_rnn) {
                int q2 = lc >> 3, jj = lc & 7;
#pragma unroll
                for (int r = 0; r < 4; ++r) {
                    int m = quad * 4 + r;    // C/D layout: row=(l>>4)*4+r
                    float x = p0[r] + p1[r] + p2[r] + p3[r] + av[r];
                    float e2 = __expf(-2.f * fabsf(x));
                    float th = copysignf((1.f - e2) / (1.f + e2), x);
                    hstage[(q2 * 16 + m) * 8 + jj] = f2bf(th);
                    if (t == TT) out[(size_t)m * DD + c0 + lc] = th;
                }
            } else {
#pragma unroll
                for (int r = 0; r < 4; ++r) {
                    int m = quad * 4 + r;
                    float y = p0[r] + p1[r] + p2[r] + p3[r];
                    ys[(size_t)((t - 1) * 16 + m) * DD + c0 + lc] = y;
                }
            }
        }

        if (is_rnn) {
            __syncthreads();   // hstage complete
            // Wave 0 publishes the block's 1 KB h slice (one 16 B store per
            // lane), acks at LLC, then stores its padded flag.
            if (w == 0) {
                char* dst = (char*)(Hf + (size_t)t * HF_SLOT + (size_t)b * 512) + l * 16;
                f32x4 v = *(const f32x4*)((const char*)hstage + l * 16);
                LLC_STORE16(dst, v);
                asm volatile("s_waitcnt vmcnt(0)" ::: "memory");   // store acked at LLC
                if (l == 0)
                    __hip_atomic_store(&flags[b * FSTRIDE], (unsigned)t,
                                       __ATOMIC_RELAXED, __HIP_MEMORY_SCOPE_AGENT);
            }
        }
        // y blocks: scr reuse at t+1 protected by the next poll barrier.
    }
}

// ---------------------------------------------------------------------------
extern "C" void kernel_launch(void* const* d_in, const int* in_sizes, int n_in,
                              void* d_out, int out_size, void* d_ws, size_t ws_size,
                              hipStream_t stream) {
    const float* h0 = (const float*)d_in[0];
    const float* x  = (const float*)d_in[1];
    const float* Wx = (const float*)d_in[2];
    const float* Wh = (const float*)d_in[3];
    const float* Wo = (const float*)d_in[4];
    float* out = (float*)d_out;

    char* ws = (char*)d_ws;
    unsigned* flags = (unsigned*)ws;                             // 4 KB (64 flags, 64B stride)
    ushort_t* Hf  = (ushort_t*)(ws + 4096);                      // 513 slots * 64KB
    ushort_t* Xf  = Hf + HF_SLOT;                                // alias slots 1..512 (dead after phase 1)
    size_t hf_bytes = (size_t)(TT + 1) * HF_SLOT * 2;
    ushort_t* Wxt = (ushort_t*)(ws + 4096 + hf_bytes);
    ushort_t* Wht = Wxt + (size_t)DD * DD;
    ushort_t* Wot = Wht + (size_t)DD * DD;
    float* A32 = out + HF_SLOT;                                  // ys region; y writes trail A32 reads

    hipMemsetAsync(d_ws, 0, 4096, stream);

    // fp32 -> bf16 layout conversions
    conv_frag<<<8192, 256, 0, stream>>>(x, Xf);                  // X fragments
    conv_frag<<<16, 256, 0, stream>>>(h0, Hf);                   // h0 -> slot 0
    conv_wt<<<2048, 256, 0, stream>>>(Wx, Wxt);
    conv_wt<<<2048, 256, 0, stream>>>(Wh, Wht);
    conv_wt<<<2048, 256, 0, stream>>>(Wo, Wot);

    // Phase 1: A32 = X @ Wx   (fp32, lives in d_out's ys region)
    gemm_frag<<<dim3(64, 16), 256, 0, stream>>>(Xf, Wxt, A32);

    // Phase 2+3 fused: recurrence + streaming y = h @ Wo
    rnn_fused<<<2 * NBLK, 256, 0, stream>>>(Wht, Wot, Hf, A32, out, flags);
}